// Round 1
// baseline (788.542 us; speedup 1.0000x reference)
//
#include <hip/hip_runtime.h>
#include <cfloat>

#define NTOK (64 * 4096)   // 262144 tokens
#define HID  128
#define NE   64
#define TK   6
#define BLK  256
#define TPB  256           // tokens per block
#define GRID (NTOK / TPB)  // 1024 blocks
#define LSTEX 33           // exchange row stride (words/token): 33%32=1 -> conflict-free b32

__global__ __launch_bounds__(BLK, 4)
void gate_kernel(const float* __restrict__ X,
                 const float* __restrict__ W,
                 float* __restrict__ oidx,
                 float* __restrict__ ow,
                 float* __restrict__ Pi_g,
                 unsigned int* __restrict__ cnt_g)
{
    // Phase GEMM: smem[0..2048)  = W rotated: Wlds[k][(e + 4*((k>>2)&15)) & 63]
    // Phase EPI : smem[0..8448)  = exchange EX[t][w][0..7] at t*33 + w*8 (overlay after barrier)
    //             EX fields: [0..5]=top6 vals desc, [6]=packed 4-bit j-indices, [7]=Z_w
    __shared__ float        smem[TPB * LSTEX];   // 33792 B
    __shared__ float        mz[2 * TPB];         // (m_t, 1/Z_t) per token
    __shared__ float        Pi_s[NE];
    __shared__ unsigned int cnt_s[NE];

    const int tid  = threadIdx.x;
    const int lane = tid & 63;
    const int wv   = __builtin_amdgcn_readfirstlane(tid >> 6);  // 0..3
    const int eb   = wv * 16;                  // this wave's 16 experts

    if (tid < NE) cnt_s[tid] = 0u;

    // ---- stage W rotated (one-time; minor 4-way conflicts, negligible)
    {
        const float4* W4 = (const float4*)W;
#pragma unroll
        for (int i = 0; i < 8; ++i) {
            const int flat = tid + i * BLK;     // [0,2048) float4 index
            const float4 v = W4[flat];
            const int e   = flat >> 5;
            const int c   = flat & 31;          // k>>2
            const int col = (e + ((c & 15) << 2)) & 63;
            float* p = &smem[c * 256 + col];    // k rows 4c..4c+3
            p[0]   = v.x;
            p[64]  = v.y;
            p[128] = v.z;
            p[192] = v.w;
        }
    }
    __syncthreads();

    const int gtok0 = blockIdx.x * TPB;
    const float4* xr0 = (const float4*)(X + (size_t)(gtok0 + lane      ) * HID);
    const float4* xr1 = (const float4*)(X + (size_t)(gtok0 + lane +  64) * HID);
    const float4* xr2 = (const float4*)(X + (size_t)(gtok0 + lane + 128) * HID);
    const float4* xr3 = (const float4*)(X + (size_t)(gtok0 + lane + 192) * HID);

    float acc[4][16];
#pragma unroll
    for (int g = 0; g < 4; ++g)
#pragma unroll
        for (int j = 0; j < 16; ++j) acc[g][j] = 0.0f;

    // ---- GEMM: wave computes 16 experts x 256 tokens (4 tokens/lane)
#pragma unroll 2
    for (int c = 0; c < 32; ++c) {             // k = 4c..4c+3
        float xs[4][4];
        {
            const float4 v0 = xr0[c], v1 = xr1[c], v2 = xr2[c], v3 = xr3[c];
            xs[0][0]=v0.x; xs[0][1]=v0.y; xs[0][2]=v0.z; xs[0][3]=v0.w;
            xs[1][0]=v1.x; xs[1][1]=v1.y; xs[1][2]=v1.z; xs[1][3]=v1.w;
            xs[2][0]=v2.x; xs[2][1]=v2.y; xs[2][2]=v2.z; xs[2][3]=v2.w;
            xs[3][0]=v3.x; xs[3][1]=v3.y; xs[3][2]=v3.z; xs[3][3]=v3.w;
        }
        const int rr = (c & 15) << 2;
        const int c0 = (eb +  0 + rr) & 63;
        const int c1 = (eb +  4 + rr) & 63;
        const int c2 = (eb +  8 + rr) & 63;
        const int c3 = (eb + 12 + rr) & 63;
        const float* rowb = &smem[c * 256];
#pragma unroll
        for (int d = 0; d < 4; ++d) {
            const float* row = rowb + d * 64;
            const float4 w0 = *(const float4*)&row[c0];   // uniform: no conflicts
            const float4 w1 = *(const float4*)&row[c1];
            const float4 w2 = *(const float4*)&row[c2];
            const float4 w3 = *(const float4*)&row[c3];
#pragma unroll
            for (int g = 0; g < 4; ++g) {
                const float xv = xs[g][d];
                acc[g][ 0] = fmaf(xv, w0.x, acc[g][ 0]);
                acc[g][ 1] = fmaf(xv, w0.y, acc[g][ 1]);
                acc[g][ 2] = fmaf(xv, w0.z, acc[g][ 2]);
                acc[g][ 3] = fmaf(xv, w0.w, acc[g][ 3]);
                acc[g][ 4] = fmaf(xv, w1.x, acc[g][ 4]);
                acc[g][ 5] = fmaf(xv, w1.y, acc[g][ 5]);
                acc[g][ 6] = fmaf(xv, w1.z, acc[g][ 6]);
                acc[g][ 7] = fmaf(xv, w1.w, acc[g][ 7]);
                acc[g][ 8] = fmaf(xv, w2.x, acc[g][ 8]);
                acc[g][ 9] = fmaf(xv, w2.y, acc[g][ 9]);
                acc[g][10] = fmaf(xv, w2.z, acc[g][10]);
                acc[g][11] = fmaf(xv, w2.w, acc[g][11]);
                acc[g][12] = fmaf(xv, w3.x, acc[g][12]);
                acc[g][13] = fmaf(xv, w3.y, acc[g][13]);
                acc[g][14] = fmaf(xv, w3.z, acc[g][14]);
                acc[g][15] = fmaf(xv, w3.w, acc[g][15]);
            }
        }
    }

    __syncthreads();   // all waves done reading W -> overlay region with exchange

    // ---- partial phase: per (token,wave) top-6-of-16 + wave-local softmax stats.
    //      acc[g][j] corresponds to expert eb+j (rotation cancels in GEMM read).
    //      Overwrite acc with exp(L - m_w) for the Pi pass (no logit re-reads).
    float m_gw[4];
#pragma unroll
    for (int g = 0; g < 4; ++g) {
        float tv[TK]; int tj[TK];
#pragma unroll
        for (int q = 0; q < TK; ++q) { tv[q] = -FLT_MAX; tj[q] = 0; }
#pragma unroll
        for (int j = 0; j < 16; ++j) {         // ascending j: jax stable tie order
            float m = acc[g][j]; int mi = j;
#pragma unroll
            for (int q = 0; q < TK; ++q) {
                const bool  cx = m > tv[q];
                const float nt = cx ? m     : tv[q];
                const float nm = cx ? tv[q] : m;
                const int   ni = cx ? mi    : tj[q];
                const int   nj = cx ? tj[q] : mi;
                tv[q] = nt; m = nm; tj[q] = ni; mi = nj;
            }
        }
        const float mw = tv[0];                // wave-local max = top-1
        m_gw[g] = mw;
        float Z = 0.0f;
#pragma unroll
        for (int j = 0; j < 16; ++j) {
            const float e = __expf(acc[g][j] - mw);
            acc[g][j] = e;                     // keep exp for Pi pass
            Z += e;
        }
        const unsigned pk = (unsigned)tj[0]        | ((unsigned)tj[1] << 4)
                          | ((unsigned)tj[2] << 8) | ((unsigned)tj[3] << 12)
                          | ((unsigned)tj[4] << 16)| ((unsigned)tj[5] << 20);
        float* p = &smem[(lane + 64 * g) * LSTEX + wv * 8];
        p[0] = tv[0]; p[1] = tv[1]; p[2] = tv[2];
        p[3] = tv[3]; p[4] = tv[4]; p[5] = tv[5];
        p[6] = __uint_as_float(pk);
        p[7] = Z;
    }
    __syncthreads();

    // ---- merge: thread = token. Merge 4 sorted 6-lists (stable: lower wave /
    //      lower index wins ties via strict >), combine softmax stats.
    {
        const int t = tid;
        const float* exb = &smem[t * LSTEX];

        float tv[TK]; int ti[TK];
        {
            const unsigned pk = __float_as_uint(exb[6]);
#pragma unroll
            for (int q = 0; q < TK; ++q) {
                tv[q] = exb[q];
                ti[q] = (int)((pk >> (4 * q)) & 15u);   // wave 0: global e = j
            }
        }
        const float mw0 = exb[0],  Za = exb[7];
        const float mw1 = exb[8],  Zb = exb[15];
        const float mw2 = exb[16], Zc = exb[23];
        const float mw3 = exb[24], Zd = exb[31];

#pragma unroll
        for (int w = 1; w < 4; ++w) {
            const float* e = exb + 8 * w;
            const unsigned pk = __float_as_uint(e[6]);
#pragma unroll
            for (int q2 = 0; q2 < TK; ++q2) {  // descending within list
                float m = e[q2];
                int  mi = 16 * w + (int)((pk >> (4 * q2)) & 15u);
#pragma unroll
                for (int q = 0; q < TK; ++q) {
                    const bool  cx = m > tv[q];
                    const float nt = cx ? m     : tv[q];
                    const float nm = cx ? tv[q] : m;
                    const int   ni = cx ? mi    : ti[q];
                    const int   nj = cx ? ti[q] : mi;
                    tv[q] = nt; m = nm; ti[q] = ni; mi = nj;
                }
            }
        }

        const float mx = tv[0];                // global max = top-1
        const float Zt = Za * __expf(mw0 - mx) + Zb * __expf(mw1 - mx)
                       + Zc * __expf(mw2 - mx) + Zd * __expf(mw3 - mx);

        float ex[TK]; float s = 0.0f;
#pragma unroll
        for (int q = 0; q < TK; ++q) { ex[q] = __expf(tv[q] - mx); s += ex[q]; }
        const float rs = 1.0f / (s + 1e-20f);

        const size_t gt = (size_t)(gtok0 + t) * TK;
        float2* ip = (float2*)(oidx + gt);
        float2* wp = (float2*)(ow + gt);
        ip[0] = make_float2((float)ti[0], (float)ti[1]);
        ip[1] = make_float2((float)ti[2], (float)ti[3]);
        ip[2] = make_float2((float)ti[4], (float)ti[5]);
        wp[0] = make_float2(ex[0]*rs, ex[1]*rs);
        wp[1] = make_float2(ex[2]*rs, ex[3]*rs);
        wp[2] = make_float2(ex[4]*rs, ex[5]*rs);

#pragma unroll
        for (int q = 0; q < TK; ++q) atomicAdd(&cnt_s[ti[q]], 1u);

        mz[2*t]     = mx;
        mz[2*t + 1] = 1.0f / Zt;
    }
    __syncthreads();

    // ---- Pi: acc already holds exp(L - m_w); rescale by exp(m_w - m_t)/Z_t.
    {
        float pi[16];
#pragma unroll
        for (int j = 0; j < 16; ++j) pi[j] = 0.0f;
#pragma unroll
        for (int g = 0; g < 4; ++g) {
            const int t = lane + 64 * g;
            const float sc = __expf(m_gw[g] - mz[2*t]) * mz[2*t + 1];
#pragma unroll
            for (int j = 0; j < 16; ++j)
                pi[j] = fmaf(acc[g][j], sc, pi[j]);
        }
        // butterfly: every lane ends with the wave-total for each of the 16 experts
#pragma unroll
        for (int s = 1; s <= 32; s <<= 1) {
#pragma unroll
            for (int j = 0; j < 16; ++j) pi[j] += __shfl_xor(pi[j], s);
        }
#pragma unroll
        for (int j = 0; j < 16; ++j)
            if (lane == j) Pi_s[eb + j] = pi[j];   // waves own disjoint experts
    }
    __syncthreads();

    if (tid < NE) {
        atomicAdd(&Pi_g[tid], Pi_s[tid]);
        atomicAdd(&cnt_g[tid], cnt_s[tid]);
    }
}

__global__ void aux_kernel(const float* __restrict__ Pi_g,
                           const unsigned int* __restrict__ cnt_g,
                           float* __restrict__ out_aux)
{
    const int e = threadIdx.x;   // 64 threads
    const float Pi = Pi_g[e] * (1.0f / (float)NTOK);
    const float ce = (float)cnt_g[e] * (1.0f / (float)(NTOK * TK));
    float v = Pi * ce * (float)NE;
#pragma unroll
    for (int off = 32; off > 0; off >>= 1) v += __shfl_down(v, off);
    if (e == 0) out_aux[0] = v * 1.0e-3f;
}

extern "C" void kernel_launch(void* const* d_in, const int* in_sizes, int n_in,
                              void* d_out, int out_size, void* d_ws, size_t ws_size,
                              hipStream_t stream) {
    const float* X = (const float*)d_in[0];
    const float* W = (const float*)d_in[1];

    float* out  = (float*)d_out;
    float* oidx = out;                          // N*6 indices (as float)
    float* ow   = out + (size_t)NTOK * TK;      // N*6 weights
    float* aux  = out + (size_t)NTOK * TK * 2;  // 1 scalar

    float*        Pi_g  = (float*)d_ws;
    unsigned int* cnt_g = (unsigned int*)((char*)d_ws + 256);

    hipMemsetAsync(d_ws, 0, 512, stream);
    gate_kernel<<<GRID, BLK, 0, stream>>>(X, W, oidx, ow, Pi_g, cnt_g);
    aux_kernel<<<1, 64, 0, stream>>>(Pi_g, cnt_g, aux);
}

// Round 2
// 267.511 us; speedup vs baseline: 2.9477x; 2.9477x over previous
//
#include <hip/hip_runtime.h>
#include <cfloat>

#define NTOK (64 * 4096)   // 262144 tokens
#define HID  128
#define NE   64
#define TK   6
#define BLK  256
#define TPB  256           // tokens per block
#define GRID (NTOK / TPB)  // 1024 blocks
#define LSTEX 33           // exchange row stride (words/token): 33%32=1 -> conflict-free b32

// __launch_bounds__ arg2: empirically on this toolchain arg=4 caps VGPR at 64
// (round-1: VGPR=64, 2.8 GB scratch spill, 652 us). arg=2 -> cap ~128, the
// GEMM needs ~120 live regs. LDS=36.4KB + VGPR<=128 => 4 blocks/CU anyway.
__global__ __launch_bounds__(BLK, 2)
void gate_kernel(const float* __restrict__ X,
                 const float* __restrict__ W,
                 float* __restrict__ oidx,
                 float* __restrict__ ow,
                 float* __restrict__ Pi_g,
                 unsigned int* __restrict__ cnt_g)
{
    // Phase GEMM: smem[0..2048)  = W rotated: Wlds[k][(e + 4*((k>>2)&15)) & 63]
    // Phase EPI : smem[0..8448)  = exchange EX[t][w][0..7] at t*33 + w*8 (overlay after barrier)
    //             EX fields: [0..5]=top6 vals desc, [6]=packed 4-bit j-indices, [7]=Z_w
    __shared__ float        smem[TPB * LSTEX];   // 33792 B
    __shared__ float        mz[2 * TPB];         // (m_t, 1/Z_t) per token
    __shared__ float        Pi_s[NE];
    __shared__ unsigned int cnt_s[NE];

    const int tid  = threadIdx.x;
    const int lane = tid & 63;
    const int wv   = __builtin_amdgcn_readfirstlane(tid >> 6);  // 0..3
    const int eb   = wv * 16;                  // this wave's 16 experts

    if (tid < NE) cnt_s[tid] = 0u;

    // ---- stage W rotated (one-time; minor 4-way conflicts, negligible)
    {
        const float4* W4 = (const float4*)W;
#pragma unroll
        for (int i = 0; i < 8; ++i) {
            const int flat = tid + i * BLK;     // [0,2048) float4 index
            const float4 v = W4[flat];
            const int e   = flat >> 5;
            const int c   = flat & 31;          // k>>2
            const int col = (e + ((c & 15) << 2)) & 63;
            float* p = &smem[c * 256 + col];    // k rows 4c..4c+3
            p[0]   = v.x;
            p[64]  = v.y;
            p[128] = v.z;
            p[192] = v.w;
        }
    }
    __syncthreads();

    const int gtok0 = blockIdx.x * TPB;
    const float4* xr0 = (const float4*)(X + (size_t)(gtok0 + lane      ) * HID);
    const float4* xr1 = (const float4*)(X + (size_t)(gtok0 + lane +  64) * HID);
    const float4* xr2 = (const float4*)(X + (size_t)(gtok0 + lane + 128) * HID);
    const float4* xr3 = (const float4*)(X + (size_t)(gtok0 + lane + 192) * HID);

    float acc[4][16];
#pragma unroll
    for (int g = 0; g < 4; ++g)
#pragma unroll
        for (int j = 0; j < 16; ++j) acc[g][j] = 0.0f;

    // ---- GEMM: wave computes 16 experts x 256 tokens (4 tokens/lane)
#pragma unroll 2
    for (int c = 0; c < 32; ++c) {             // k = 4c..4c+3
        float xs[4][4];
        {
            const float4 v0 = xr0[c], v1 = xr1[c], v2 = xr2[c], v3 = xr3[c];
            xs[0][0]=v0.x; xs[0][1]=v0.y; xs[0][2]=v0.z; xs[0][3]=v0.w;
            xs[1][0]=v1.x; xs[1][1]=v1.y; xs[1][2]=v1.z; xs[1][3]=v1.w;
            xs[2][0]=v2.x; xs[2][1]=v2.y; xs[2][2]=v2.z; xs[2][3]=v2.w;
            xs[3][0]=v3.x; xs[3][1]=v3.y; xs[3][2]=v3.z; xs[3][3]=v3.w;
        }
        const int rr = (c & 15) << 2;
        const int c0 = (eb +  0 + rr) & 63;
        const int c1 = (eb +  4 + rr) & 63;
        const int c2 = (eb +  8 + rr) & 63;
        const int c3 = (eb + 12 + rr) & 63;
        const float* rowb = &smem[c * 256];
#pragma unroll
        for (int d = 0; d < 4; ++d) {
            const float* row = rowb + d * 64;
            const float4 w0 = *(const float4*)&row[c0];   // uniform: no conflicts
            const float4 w1 = *(const float4*)&row[c1];
            const float4 w2 = *(const float4*)&row[c2];
            const float4 w3 = *(const float4*)&row[c3];
#pragma unroll
            for (int g = 0; g < 4; ++g) {
                const float xv = xs[g][d];
                acc[g][ 0] = fmaf(xv, w0.x, acc[g][ 0]);
                acc[g][ 1] = fmaf(xv, w0.y, acc[g][ 1]);
                acc[g][ 2] = fmaf(xv, w0.z, acc[g][ 2]);
                acc[g][ 3] = fmaf(xv, w0.w, acc[g][ 3]);
                acc[g][ 4] = fmaf(xv, w1.x, acc[g][ 4]);
                acc[g][ 5] = fmaf(xv, w1.y, acc[g][ 5]);
                acc[g][ 6] = fmaf(xv, w1.z, acc[g][ 6]);
                acc[g][ 7] = fmaf(xv, w1.w, acc[g][ 7]);
                acc[g][ 8] = fmaf(xv, w2.x, acc[g][ 8]);
                acc[g][ 9] = fmaf(xv, w2.y, acc[g][ 9]);
                acc[g][10] = fmaf(xv, w2.z, acc[g][10]);
                acc[g][11] = fmaf(xv, w2.w, acc[g][11]);
                acc[g][12] = fmaf(xv, w3.x, acc[g][12]);
                acc[g][13] = fmaf(xv, w3.y, acc[g][13]);
                acc[g][14] = fmaf(xv, w3.z, acc[g][14]);
                acc[g][15] = fmaf(xv, w3.w, acc[g][15]);
            }
        }
    }

    __syncthreads();   // all waves done reading W -> overlay region with exchange

    // ---- partial phase: per (token,wave) top-6-of-16 + wave-local softmax stats.
    //      acc[g][j] corresponds to expert eb+j (rotation cancels in GEMM read).
    //      Overwrite acc with exp(L - m_w) for the Pi pass (no logit re-reads).
    float m_gw[4];
#pragma unroll
    for (int g = 0; g < 4; ++g) {
        float tv[TK]; int tj[TK];
#pragma unroll
        for (int q = 0; q < TK; ++q) { tv[q] = -FLT_MAX; tj[q] = 0; }
#pragma unroll
        for (int j = 0; j < 16; ++j) {         // ascending j: jax stable tie order
            float m = acc[g][j]; int mi = j;
#pragma unroll
            for (int q = 0; q < TK; ++q) {
                const bool  cx = m > tv[q];
                const float nt = cx ? m     : tv[q];
                const float nm = cx ? tv[q] : m;
                const int   ni = cx ? mi    : tj[q];
                const int   nj = cx ? tj[q] : mi;
                tv[q] = nt; m = nm; tj[q] = ni; mi = nj;
            }
        }
        const float mw = tv[0];                // wave-local max = top-1
        m_gw[g] = mw;
        float Z = 0.0f;
#pragma unroll
        for (int j = 0; j < 16; ++j) {
            const float e = __expf(acc[g][j] - mw);
            acc[g][j] = e;                     // keep exp for Pi pass
            Z += e;
        }
        const unsigned pk = (unsigned)tj[0]        | ((unsigned)tj[1] << 4)
                          | ((unsigned)tj[2] << 8) | ((unsigned)tj[3] << 12)
                          | ((unsigned)tj[4] << 16)| ((unsigned)tj[5] << 20);
        float* p = &smem[(lane + 64 * g) * LSTEX + wv * 8];
        p[0] = tv[0]; p[1] = tv[1]; p[2] = tv[2];
        p[3] = tv[3]; p[4] = tv[4]; p[5] = tv[5];
        p[6] = __uint_as_float(pk);
        p[7] = Z;
    }
    __syncthreads();

    // ---- merge: thread = token. Merge 4 sorted 6-lists (stable: lower wave /
    //      lower index wins ties via strict >), combine softmax stats.
    {
        const int t = tid;
        const float* exb = &smem[t * LSTEX];

        float tv[TK]; int ti[TK];
        {
            const unsigned pk = __float_as_uint(exb[6]);
#pragma unroll
            for (int q = 0; q < TK; ++q) {
                tv[q] = exb[q];
                ti[q] = (int)((pk >> (4 * q)) & 15u);   // wave 0: global e = j
            }
        }
        const float mw0 = exb[0],  Za = exb[7];
        const float mw1 = exb[8],  Zb = exb[15];
        const float mw2 = exb[16], Zc = exb[23];
        const float mw3 = exb[24], Zd = exb[31];

#pragma unroll
        for (int w = 1; w < 4; ++w) {
            const float* e = exb + 8 * w;
            const unsigned pk = __float_as_uint(e[6]);
#pragma unroll
            for (int q2 = 0; q2 < TK; ++q2) {  // descending within list
                float m = e[q2];
                int  mi = 16 * w + (int)((pk >> (4 * q2)) & 15u);
#pragma unroll
                for (int q = 0; q < TK; ++q) {
                    const bool  cx = m > tv[q];
                    const float nt = cx ? m     : tv[q];
                    const float nm = cx ? tv[q] : m;
                    const int   ni = cx ? mi    : ti[q];
                    const int   nj = cx ? ti[q] : mi;
                    tv[q] = nt; m = nm; ti[q] = ni; mi = nj;
                }
            }
        }

        const float mx = tv[0];                // global max = top-1
        const float Zt = Za * __expf(mw0 - mx) + Zb * __expf(mw1 - mx)
                       + Zc * __expf(mw2 - mx) + Zd * __expf(mw3 - mx);

        float ex[TK]; float s = 0.0f;
#pragma unroll
        for (int q = 0; q < TK; ++q) { ex[q] = __expf(tv[q] - mx); s += ex[q]; }
        const float rs = 1.0f / (s + 1e-20f);

        const size_t gt = (size_t)(gtok0 + t) * TK;
        float2* ip = (float2*)(oidx + gt);
        float2* wp = (float2*)(ow + gt);
        ip[0] = make_float2((float)ti[0], (float)ti[1]);
        ip[1] = make_float2((float)ti[2], (float)ti[3]);
        ip[2] = make_float2((float)ti[4], (float)ti[5]);
        wp[0] = make_float2(ex[0]*rs, ex[1]*rs);
        wp[1] = make_float2(ex[2]*rs, ex[3]*rs);
        wp[2] = make_float2(ex[4]*rs, ex[5]*rs);

#pragma unroll
        for (int q = 0; q < TK; ++q) atomicAdd(&cnt_s[ti[q]], 1u);

        mz[2*t]     = mx;
        mz[2*t + 1] = 1.0f / Zt;
    }
    __syncthreads();

    // ---- Pi: acc already holds exp(L - m_w); rescale by exp(m_w - m_t)/Z_t.
    {
        float pi[16];
#pragma unroll
        for (int j = 0; j < 16; ++j) pi[j] = 0.0f;
#pragma unroll
        for (int g = 0; g < 4; ++g) {
            const int t = lane + 64 * g;
            const float sc = __expf(m_gw[g] - mz[2*t]) * mz[2*t + 1];
#pragma unroll
            for (int j = 0; j < 16; ++j)
                pi[j] = fmaf(acc[g][j], sc, pi[j]);
        }
        // butterfly: every lane ends with the wave-total for each of the 16 experts
#pragma unroll
        for (int s = 1; s <= 32; s <<= 1) {
#pragma unroll
            for (int j = 0; j < 16; ++j) pi[j] += __shfl_xor(pi[j], s);
        }
#pragma unroll
        for (int j = 0; j < 16; ++j)
            if (lane == j) Pi_s[eb + j] = pi[j];   // waves own disjoint experts
    }
    __syncthreads();

    if (tid < NE) {
        atomicAdd(&Pi_g[tid], Pi_s[tid]);
        atomicAdd(&cnt_g[tid], cnt_s[tid]);
    }
}

__global__ void aux_kernel(const float* __restrict__ Pi_g,
                           const unsigned int* __restrict__ cnt_g,
                           float* __restrict__ out_aux)
{
    const int e = threadIdx.x;   // 64 threads
    const float Pi = Pi_g[e] * (1.0f / (float)NTOK);
    const float ce = (float)cnt_g[e] * (1.0f / (float)(NTOK * TK));
    float v = Pi * ce * (float)NE;
#pragma unroll
    for (int off = 32; off > 0; off >>= 1) v += __shfl_down(v, off);
    if (e == 0) out_aux[0] = v * 1.0e-3f;
}

extern "C" void kernel_launch(void* const* d_in, const int* in_sizes, int n_in,
                              void* d_out, int out_size, void* d_ws, size_t ws_size,
                              hipStream_t stream) {
    const float* X = (const float*)d_in[0];
    const float* W = (const float*)d_in[1];

    float* out  = (float*)d_out;
    float* oidx = out;                          // N*6 indices (as float)
    float* ow   = out + (size_t)NTOK * TK;      // N*6 weights
    float* aux  = out + (size_t)NTOK * TK * 2;  // 1 scalar

    float*        Pi_g  = (float*)d_ws;
    unsigned int* cnt_g = (unsigned int*)((char*)d_ws + 256);

    hipMemsetAsync(d_ws, 0, 512, stream);
    gate_kernel<<<GRID, BLK, 0, stream>>>(X, W, oidx, ow, Pi_g, cnt_g);
    aux_kernel<<<1, 64, 0, stream>>>(Pi_g, cnt_g, aux);
}

// Round 5
// 265.405 us; speedup vs baseline: 2.9711x; 1.0079x over previous
//
#include <hip/hip_runtime.h>
#include <cfloat>

#define NTOK (64 * 4096)   // 262144 tokens
#define HID  128
#define NE   64
#define TK   6
#define TS   7             // sort depth: top-7 needed for the safety gap test
#define BLK  256
#define TPB  256           // tokens per block
#define GRID (NTOK / TPB)  // 1024 blocks
#define THETA 1e-4f        // gap threshold; MFMA logit err ~5e-6 << THETA/2

typedef __attribute__((ext_vector_type(8))) short short8;  // 8 bf16 (4 VGPRs)
typedef __attribute__((ext_vector_type(4))) float f32x4;   // MFMA C/D

union UB { uint4 u; short8 s; };
__device__ __forceinline__ short8 u2s(const uint4 u) { UB x; x.u = u; return x.s; }

// Dekker truncation split: a = a1 + a2 + a3 EXACTLY (bf16 terms, fp32 source).
__device__ __forceinline__ void split2(float a, float b,
                                       unsigned& d1, unsigned& d2, unsigned& d3) {
    const unsigned ua = __float_as_uint(a), ub = __float_as_uint(b);
    const unsigned ha = ua & 0xFFFF0000u,  hb = ub & 0xFFFF0000u;
    const float r1a = a - __uint_as_float(ha);
    const float r1b = b - __uint_as_float(hb);
    const unsigned ra = __float_as_uint(r1a), rb = __float_as_uint(r1b);
    const unsigned ga = ra & 0xFFFF0000u,     gb = rb & 0xFFFF0000u;
    const float r2a = r1a - __uint_as_float(ga);
    const float r2b = r1b - __uint_as_float(gb);
    d1 = (ua >> 16) | hb;
    d2 = (ra >> 16) | gb;
    d3 = (__float_as_uint(r2a) >> 16) | (__float_as_uint(r2b) & 0xFFFF0000u);
}

__device__ __forceinline__ void split8(const float4 v0, const float4 v1,
                                       uint4& o1, uint4& o2, uint4& o3) {
    split2(v0.x, v0.y, o1.x, o2.x, o3.x);
    split2(v0.z, v0.w, o1.y, o2.y, o3.y);
    split2(v1.x, v1.y, o1.z, o2.z, o3.z);
    split2(v1.z, v1.w, o1.w, o2.w, o3.w);
}

// Validated by R3/R4 bisect: MFMA logits are structurally correct (absmax 41
// << 63 => only near-tie flips). This round adds: top-7 gap flag + in-block
// fp32 rescue (bit-identical to the proven round-0 serial computation).
__global__ __launch_bounds__(BLK)
void gate_kernel(const float* __restrict__ X,
                 const float* __restrict__ W,
                 float* __restrict__ oidx,
                 float* __restrict__ ow,
                 float* __restrict__ Pi_g,
                 unsigned int* __restrict__ cnt_g)
{
    __shared__ uint4        Wlds[3 * 1024];   // 48 KB: Dekker-split W frags
    __shared__ float        Pi_s[4][NE];
    __shared__ unsigned int cnt_s[NE];
    __shared__ unsigned int flags_s[TPB];     // flagged token-local ids
    __shared__ unsigned int nflag_s;

    const int tid  = threadIdx.x;
    const int lane = tid & 63;
    const int wv   = __builtin_amdgcn_readfirstlane(tid >> 6);  // 0..3
    const int col  = lane & 15;
    const int g    = lane >> 4;

    if (tid < NE) cnt_s[tid] = 0u;
    if (tid == 0) nflag_s = 0u;

    // ---- one-time: Dekker-split W (64x128 f32) into 3 bf16 frag arrays
    {
        const float4* W4 = (const float4*)W;
#pragma unroll
        for (int i = 0; i < 4; ++i) {
            const int slot = tid + i * BLK;          // [0,1024) = fid*64 + ln
            const int fid  = slot >> 6;              // et*4 + kt
            const int ln   = slot & 63;
            const int e    = ((fid >> 2) << 4) + (ln & 15);
            const int kq   = ((fid & 3) << 3) + ((ln >> 4) << 1);
            const float4 v0 = W4[e * 32 + kq];
            const float4 v1 = W4[e * 32 + kq + 1];
            uint4 o1, o2, o3;
            split8(v0, v1, o1, o2, o3);
            Wlds[slot]        = o1;
            Wlds[1024 + slot] = o2;
            Wlds[2048 + slot] = o3;
        }
    }
    __syncthreads();

    const int tok0 = blockIdx.x * TPB + wv * 64;

    f32x4 acc[4][4];   // [tt][et]
#pragma unroll
    for (int tt = 0; tt < 4; ++tt)
#pragma unroll
        for (int et = 0; et < 4; ++et) acc[tt][et] = (f32x4)0.0f;

    // ---- GEMM (R3/R4-validated): 4 kt x {X-splits, 4 et x 8 products}
#pragma unroll
    for (int kt = 0; kt < 4; ++kt) {
        uint4 xs[3][4];   // [split][tt]
#pragma unroll
        for (int tt = 0; tt < 4; ++tt) {
            const float4* xp = (const float4*)(X + (size_t)(tok0 + tt * 16 + col) * HID)
                               + (kt * 8 + g * 2);
            split8(xp[0], xp[1], xs[0][tt], xs[1][tt], xs[2][tt]);
        }
#pragma unroll
        for (int et = 0; et < 4; ++et) {
            const int fb = ((et << 2) + kt) * 64 + lane;
            const short8 w1 = u2s(Wlds[fb]);
            const short8 w2 = u2s(Wlds[1024 + fb]);
            const short8 w3 = u2s(Wlds[2048 + fb]);
#define MM4(WF, XI) { \
            acc[0][et] = __builtin_amdgcn_mfma_f32_16x16x32_bf16(WF, u2s(xs[XI][0]), acc[0][et], 0, 0, 0); \
            acc[1][et] = __builtin_amdgcn_mfma_f32_16x16x32_bf16(WF, u2s(xs[XI][1]), acc[1][et], 0, 0, 0); \
            acc[2][et] = __builtin_amdgcn_mfma_f32_16x16x32_bf16(WF, u2s(xs[XI][2]), acc[2][et], 0, 0, 0); \
            acc[3][et] = __builtin_amdgcn_mfma_f32_16x16x32_bf16(WF, u2s(xs[XI][3]), acc[3][et], 0, 0, 0); }
            MM4(w1, 0) MM4(w1, 1) MM4(w2, 0) MM4(w1, 2)
            MM4(w3, 0) MM4(w2, 1) MM4(w3, 1) MM4(w2, 2)
#undef MM4
        }
    }

    // ---- epilogue: registers + shuffles (R3-validated via R4 bisect).
    // acc[tt][et][r] = logit(token = tok0+tt*16+col, expert = et*16+g*4+r)
    float pi[16];
#pragma unroll
    for (int j = 0; j < 16; ++j) pi[j] = 0.0f;

#pragma unroll
    for (int tt = 0; tt < 4; ++tt) {
        float tv[TS]; int te[TS];
#pragma unroll
        for (int q = 0; q < TS; ++q) { tv[q] = -FLT_MAX; te[q] = 0; }
#pragma unroll
        for (int j = 0; j < 16; ++j) {
            float m = acc[tt][j >> 2][j & 3];
            int  mi = ((j >> 2) << 4) + (g << 2) + (j & 3);
#pragma unroll
            for (int q = 0; q < TS; ++q) {
                const bool  cx = m > tv[q];
                const float nt = cx ? m     : tv[q];
                const float nm = cx ? tv[q] : m;
                const int   ni = cx ? mi    : te[q];
                const int   nj = cx ? te[q] : mi;
                tv[q] = nt; m = nm; te[q] = ni; mi = nj;
            }
        }
        const float ml = tv[0];
        float Zl = 0.0f;
#pragma unroll
        for (int j = 0; j < 16; ++j) {
            const float e = __expf(acc[tt][j >> 2][j & 3] - ml);
            acc[tt][j >> 2][j & 3] = e;         // keep exp for Pi pass
            Zl += e;
        }
        float m_self = ml, Z = Zl;
#pragma unroll
        for (int lv = 16; lv <= 32; lv <<= 1) {
            float rv[TS];
#pragma unroll
            for (int q = 0; q < TS; ++q) rv[q] = __shfl_xor(tv[q], lv);
            const unsigned pk0 = (unsigned)te[0] | ((unsigned)te[1] << 8)
                               | ((unsigned)te[2] << 16) | ((unsigned)te[3] << 24);
            const unsigned pk1 = (unsigned)te[4] | ((unsigned)te[5] << 8)
                               | ((unsigned)te[6] << 16);
            const unsigned qk0 = (unsigned)__shfl_xor((int)pk0, lv);
            const unsigned qk1 = (unsigned)__shfl_xor((int)pk1, lv);
            const float m_p = rv[0];
            const float Z_p = __shfl_xor(Z, lv);
            int re[TS];
            re[0] = qk0 & 255; re[1] = (qk0 >> 8) & 255; re[2] = (qk0 >> 16) & 255;
            re[3] = qk0 >> 24; re[4] = qk1 & 255; re[5] = (qk1 >> 8) & 255;
            re[6] = (qk1 >> 16) & 255;
#pragma unroll
            for (int q2 = 0; q2 < TS; ++q2) {
                float m = rv[q2]; int mi = re[q2];
#pragma unroll
                for (int q = 0; q < TS; ++q) {
                    const bool  cx = m > tv[q];
                    const float nt = cx ? m     : tv[q];
                    const float nm = cx ? tv[q] : m;
                    const int   ni = cx ? mi    : te[q];
                    const int   nj = cx ? te[q] : mi;
                    tv[q] = nt; m = nm; te[q] = ni; mi = nj;
                }
            }
            const float m_n = tv[0];
            Z = Z * __expf(m_self - m_n) + Z_p * __expf(m_p - m_n);
            m_self = m_n;
        }
        const float mx  = tv[0];
        const float rzt = 1.0f / Z;
        float ex[TK]; float s = 0.0f;
#pragma unroll
        for (int q = 0; q < TK; ++q) { ex[q] = __expf(tv[q] - mx); s += ex[q]; }
        const float rs = 1.0f / (s + 1e-20f);
        if (g == tt) {                          // writer lane: token = tok0 + lane
            bool flag = false;
#pragma unroll
            for (int q = 0; q < TK; ++q) flag |= (tv[q] - tv[q + 1]) < THETA;
            const size_t gt = (size_t)(tok0 + lane) * TK;
            float2* ip = (float2*)(oidx + gt);
            float2* wp = (float2*)(ow + gt);
            ip[0] = make_float2((float)te[0], (float)te[1]);
            ip[1] = make_float2((float)te[2], (float)te[3]);
            ip[2] = make_float2((float)te[4], (float)te[5]);
            wp[0] = make_float2(ex[0] * rs, ex[1] * rs);
            wp[1] = make_float2(ex[2] * rs, ex[3] * rs);
            wp[2] = make_float2(ex[4] * rs, ex[5] * rs);
            if (!flag) {
#pragma unroll
                for (int q = 0; q < TK; ++q) atomicAdd(&cnt_s[te[q]], 1u);
            } else {
                const unsigned slot = atomicAdd(&nflag_s, 1u);
                flags_s[slot] = (unsigned)(wv * 64 + lane);  // <= 256 pushes
            }
        }
        const float sc = __expf(ml - mx) * rzt;
#pragma unroll
        for (int j = 0; j < 16; ++j)
            pi[j] = fmaf(acc[tt][j >> 2][j & 3], sc, pi[j]);
    }

    // Pi reduce across the 16 col-lanes sharing this lane's expert set
#pragma unroll
    for (int sh = 1; sh <= 8; sh <<= 1)
#pragma unroll
        for (int j = 0; j < 16; ++j) pi[j] += __shfl_xor(pi[j], sh);
    if (col == 0) {
#pragma unroll
        for (int j = 0; j < 16; ++j)
            Pi_s[wv][((j >> 2) << 4) + (g << 2) + (j & 3)] = pi[j];
    }
    __syncthreads();

    // ---- rescue: fp32 rescore flagged tokens, bit-identical to round-0 math.
    // One wave per flagged token; lane = expert; serial ascending-k fmaf chain.
    {
        const int nf = (int)nflag_s;            // uniform after barrier
        for (int i = wv; i < nf; i += 4) {
            const int tl = (int)flags_s[i];
            const float4* xr = (const float4*)(X + (size_t)(blockIdx.x * TPB + tl) * HID);
            const float4* wr = (const float4*)(W + (size_t)lane * HID);
            float a = 0.0f;
#pragma unroll 8
            for (int kq = 0; kq < 32; ++kq) {   // k strictly ascending 0..127
                const float4 xv = xr[kq];
                const float4 wv4 = wr[kq];
                a = fmaf(xv.x, wv4.x, a);
                a = fmaf(xv.y, wv4.y, a);
                a = fmaf(xv.z, wv4.z, a);
                a = fmaf(xv.w, wv4.w, a);
            }
            // broadcast all 64 logits; every lane runs the serial top-6
            float tv[TK]; int ti[TK];
#pragma unroll
            for (int q = 0; q < TK; ++q) { tv[q] = -FLT_MAX; ti[q] = 0; }
            for (int e = 0; e < NE; ++e) {      // ascending e: stable tie order
                float m = __shfl(a, e);
                int  mi = e;
#pragma unroll
                for (int q = 0; q < TK; ++q) {
                    const bool  cx = m > tv[q];
                    const float nt = cx ? m     : tv[q];
                    const float nm = cx ? tv[q] : m;
                    const int   ni = cx ? mi    : ti[q];
                    const int   nj = cx ? ti[q] : mi;
                    tv[q] = nt; m = nm; ti[q] = ni; mi = nj;
                }
            }
            const float mx = tv[0];
            float ex[TK]; float s = 0.0f;
#pragma unroll
            for (int q = 0; q < TK; ++q) { ex[q] = __expf(tv[q] - mx); s += ex[q]; }
            const float rs = 1.0f / (s + 1e-20f);
            if (lane == 0) {
                const size_t gt = (size_t)(blockIdx.x * TPB + tl) * TK;
                float2* ip = (float2*)(oidx + gt);
                float2* wp = (float2*)(ow + gt);
                ip[0] = make_float2((float)ti[0], (float)ti[1]);
                ip[1] = make_float2((float)ti[2], (float)ti[3]);
                ip[2] = make_float2((float)ti[4], (float)ti[5]);
                wp[0] = make_float2(ex[0] * rs, ex[1] * rs);
                wp[1] = make_float2(ex[2] * rs, ex[3] * rs);
                wp[2] = make_float2(ex[4] * rs, ex[5] * rs);
#pragma unroll
                for (int q = 0; q < TK; ++q) atomicAdd(&cnt_s[ti[q]], 1u);
            }
        }
    }
    __syncthreads();

    if (tid < NE) {
        atomicAdd(&Pi_g[tid], Pi_s[0][tid] + Pi_s[1][tid] + Pi_s[2][tid] + Pi_s[3][tid]);
        atomicAdd(&cnt_g[tid], cnt_s[tid]);
    }
}

__global__ void aux_kernel(const float* __restrict__ Pi_g,
                           const unsigned int* __restrict__ cnt_g,
                           float* __restrict__ out_aux)
{
    const int e = threadIdx.x;   // 64 threads
    const float Pi = Pi_g[e] * (1.0f / (float)NTOK);
    const float ce = (float)cnt_g[e] * (1.0f / (float)(NTOK * TK));
    float v = Pi * ce * (float)NE;
#pragma unroll
    for (int off = 32; off > 0; off >>= 1) v += __shfl_down(v, off);
    if (e == 0) out_aux[0] = v * 1.0e-3f;
}

extern "C" void kernel_launch(void* const* d_in, const int* in_sizes, int n_in,
                              void* d_out, int out_size, void* d_ws, size_t ws_size,
                              hipStream_t stream) {
    const float* X = (const float*)d_in[0];
    const float* W = (const float*)d_in[1];

    float* out  = (float*)d_out;
    float* oidx = out;                          // N*6 indices (as float)
    float* ow   = out + (size_t)NTOK * TK;      // N*6 weights
    float* aux  = out + (size_t)NTOK * TK * 2;  // 1 scalar

    float*        Pi_g  = (float*)d_ws;
    unsigned int* cnt_g = (unsigned int*)((char*)d_ws + 256);

    hipMemsetAsync(d_ws, 0, 512, stream);
    gate_kernel<<<GRID, BLK, 0, stream>>>(X, W, oidx, ow, Pi_g, cnt_g);
    aux_kernel<<<1, 64, 0, stream>>>(Pi_g, cnt_g, aux);
}

// Round 6
// 265.148 us; speedup vs baseline: 2.9740x; 1.0010x over previous
//
#include <hip/hip_runtime.h>
#include <cfloat>

#define NTOK (64 * 4096)   // 262144 tokens
#define HID  128
#define NE   64
#define TK   6
#define TS   7             // sort depth: top-7 needed for the safety gap test
#define BLK  256
#define TPB  256           // tokens per block
#define GRID (NTOK / TPB)  // 1024 blocks = exactly 4/CU -> zero tail at 4 blk/CU
#define THETA 2e-4f        // gap threshold; 2x2-split logit err <~3e-5 << THETA/2

typedef __attribute__((ext_vector_type(8))) short short8;  // 8 bf16 (4 VGPRs)
typedef __attribute__((ext_vector_type(4))) float f32x4;   // MFMA C/D

union UB { uint4 u; short8 s; };
__device__ __forceinline__ short8 u2s(const uint4 u) { UB x; x.u = u; return x.s; }

// 2-term round-to-nearest split: a ~= a1 + a2, |a - a1 - a2| <= 2^-18 |a|.
// v_cvt_pk_bf16_f32 does RNE + pair-packing in one instruction; packing
// (a -> low16, b -> high16) is IDENTICAL to the R4/R5-validated layout.
__device__ __forceinline__ void split2(float a, float b, unsigned& d1, unsigned& d2) {
    unsigned p1;
    asm("v_cvt_pk_bf16_f32 %0, %1, %2" : "=v"(p1) : "v"(a), "v"(b));
    const float a1 = __uint_as_float(p1 << 16);
    const float b1 = __uint_as_float(p1 & 0xFFFF0000u);
    const float ra = a - a1;   // exact (Sterbenz: a1 = RNE(a) within 2^-9)
    const float rb = b - b1;
    unsigned p2;
    asm("v_cvt_pk_bf16_f32 %0, %1, %2" : "=v"(p2) : "v"(ra), "v"(rb));
    d1 = p1; d2 = p2;
}

__device__ __forceinline__ void split8(const float4 v0, const float4 v1,
                                       uint4& o1, uint4& o2) {
    split2(v0.x, v0.y, o1.x, o2.x);
    split2(v0.z, v0.w, o1.y, o2.y);
    split2(v1.x, v1.y, o1.z, o2.z);
    split2(v1.z, v1.w, o1.w, o2.w);
}

// R5-validated architecture: MFMA GEMM + top-7 gap flag + in-block fp32
// rescue (bit-identical to the round-0 proven serial computation).
// R6 change: 3-term truncation split -> 2-term RNE split (4 product sets,
// 32 KB W-frag LDS -> 4 blocks/CU, zero grid tail). THETA 1e-4 -> 2e-4.
__global__ __launch_bounds__(BLK)
void gate_kernel(const float* __restrict__ X,
                 const float* __restrict__ W,
                 float* __restrict__ oidx,
                 float* __restrict__ ow,
                 float* __restrict__ Pi_g,
                 unsigned int* __restrict__ cnt_g)
{
    __shared__ uint4        Wlds[2 * 1024];   // 32 KB: RNE-split W frags
    __shared__ float        Pi_s[4][NE];
    __shared__ unsigned int cnt_s[NE];
    __shared__ unsigned int flags_s[TPB];     // flagged token-local ids
    __shared__ unsigned int nflag_s;

    const int tid  = threadIdx.x;
    const int lane = tid & 63;
    const int wv   = __builtin_amdgcn_readfirstlane(tid >> 6);  // 0..3
    const int col  = lane & 15;
    const int g    = lane >> 4;

    if (tid < NE) cnt_s[tid] = 0u;
    if (tid == 0) nflag_s = 0u;

    // ---- one-time: RNE-split W (64x128 f32) into 2 bf16 frag arrays
    {
        const float4* W4 = (const float4*)W;
#pragma unroll
        for (int i = 0; i < 4; ++i) {
            const int slot = tid + i * BLK;          // [0,1024) = fid*64 + ln
            const int fid  = slot >> 6;              // et*4 + kt
            const int ln   = slot & 63;
            const int e    = ((fid >> 2) << 4) + (ln & 15);
            const int kq   = ((fid & 3) << 3) + ((ln >> 4) << 1);
            const float4 v0 = W4[e * 32 + kq];
            const float4 v1 = W4[e * 32 + kq + 1];
            uint4 o1, o2;
            split8(v0, v1, o1, o2);
            Wlds[slot]        = o1;
            Wlds[1024 + slot] = o2;
        }
    }
    __syncthreads();

    const int tok0 = blockIdx.x * TPB + wv * 64;

    f32x4 acc[4][4];   // [tt][et]
#pragma unroll
    for (int tt = 0; tt < 4; ++tt)
#pragma unroll
        for (int et = 0; et < 4; ++et) acc[tt][et] = (f32x4)0.0f;

    // ---- GEMM: 4 kt x {X-splits, 4 et x 4 products (w1x1,w1x2,w2x1,w2x2)}
#pragma unroll
    for (int kt = 0; kt < 4; ++kt) {
        uint4 xs[2][4];   // [split][tt]
#pragma unroll
        for (int tt = 0; tt < 4; ++tt) {
            const float4* xp = (const float4*)(X + (size_t)(tok0 + tt * 16 + col) * HID)
                               + (kt * 8 + g * 2);
            split8(xp[0], xp[1], xs[0][tt], xs[1][tt]);
        }
#pragma unroll
        for (int et = 0; et < 4; ++et) {
            const int fb = ((et << 2) + kt) * 64 + lane;
            const short8 w1 = u2s(Wlds[fb]);
            const short8 w2 = u2s(Wlds[1024 + fb]);
#define MM4(WF, XI) { \
            acc[0][et] = __builtin_amdgcn_mfma_f32_16x16x32_bf16(WF, u2s(xs[XI][0]), acc[0][et], 0, 0, 0); \
            acc[1][et] = __builtin_amdgcn_mfma_f32_16x16x32_bf16(WF, u2s(xs[XI][1]), acc[1][et], 0, 0, 0); \
            acc[2][et] = __builtin_amdgcn_mfma_f32_16x16x32_bf16(WF, u2s(xs[XI][2]), acc[2][et], 0, 0, 0); \
            acc[3][et] = __builtin_amdgcn_mfma_f32_16x16x32_bf16(WF, u2s(xs[XI][3]), acc[3][et], 0, 0, 0); }
            MM4(w1, 0) MM4(w1, 1) MM4(w2, 0) MM4(w2, 1)
#undef MM4
        }
    }

    // ---- epilogue (R5-proven, unchanged): registers + shuffles.
    // acc[tt][et][r] = logit(token = tok0+tt*16+col, expert = et*16+g*4+r)
    float pi[16];
#pragma unroll
    for (int j = 0; j < 16; ++j) pi[j] = 0.0f;

#pragma unroll
    for (int tt = 0; tt < 4; ++tt) {
        float tv[TS]; int te[TS];
#pragma unroll
        for (int q = 0; q < TS; ++q) { tv[q] = -FLT_MAX; te[q] = 0; }
#pragma unroll
        for (int j = 0; j < 16; ++j) {
            float m = acc[tt][j >> 2][j & 3];
            int  mi = ((j >> 2) << 4) + (g << 2) + (j & 3);
#pragma unroll
            for (int q = 0; q < TS; ++q) {
                const bool  cx = m > tv[q];
                const float nt = cx ? m     : tv[q];
                const float nm = cx ? tv[q] : m;
                const int   ni = cx ? mi    : te[q];
                const int   nj = cx ? te[q] : mi;
                tv[q] = nt; m = nm; te[q] = ni; mi = nj;
            }
        }
        const float ml = tv[0];
        float Zl = 0.0f;
#pragma unroll
        for (int j = 0; j < 16; ++j) {
            const float e = __expf(acc[tt][j >> 2][j & 3] - ml);
            acc[tt][j >> 2][j & 3] = e;         // keep exp for Pi pass
            Zl += e;
        }
        float m_self = ml, Z = Zl;
#pragma unroll
        for (int lv = 16; lv <= 32; lv <<= 1) {
            float rv[TS];
#pragma unroll
            for (int q = 0; q < TS; ++q) rv[q] = __shfl_xor(tv[q], lv);
            const unsigned pk0 = (unsigned)te[0] | ((unsigned)te[1] << 8)
                               | ((unsigned)te[2] << 16) | ((unsigned)te[3] << 24);
            const unsigned pk1 = (unsigned)te[4] | ((unsigned)te[5] << 8)
                               | ((unsigned)te[6] << 16);
            const unsigned qk0 = (unsigned)__shfl_xor((int)pk0, lv);
            const unsigned qk1 = (unsigned)__shfl_xor((int)pk1, lv);
            const float m_p = rv[0];
            const float Z_p = __shfl_xor(Z, lv);
            int re[TS];
            re[0] = qk0 & 255; re[1] = (qk0 >> 8) & 255; re[2] = (qk0 >> 16) & 255;
            re[3] = qk0 >> 24; re[4] = qk1 & 255; re[5] = (qk1 >> 8) & 255;
            re[6] = (qk1 >> 16) & 255;
#pragma unroll
            for (int q2 = 0; q2 < TS; ++q2) {
                float m = rv[q2]; int mi = re[q2];
#pragma unroll
                for (int q = 0; q < TS; ++q) {
                    const bool  cx = m > tv[q];
                    const float nt = cx ? m     : tv[q];
                    const float nm = cx ? tv[q] : m;
                    const int   ni = cx ? mi    : te[q];
                    const int   nj = cx ? te[q] : mi;
                    tv[q] = nt; m = nm; te[q] = ni; mi = nj;
                }
            }
            const float m_n = tv[0];
            Z = Z * __expf(m_self - m_n) + Z_p * __expf(m_p - m_n);
            m_self = m_n;
        }
        const float mx  = tv[0];
        const float rzt = 1.0f / Z;
        float ex[TK]; float s = 0.0f;
#pragma unroll
        for (int q = 0; q < TK; ++q) { ex[q] = __expf(tv[q] - mx); s += ex[q]; }
        const float rs = 1.0f / (s + 1e-20f);
        if (g == tt) {                          // writer lane: token = tok0 + lane
            bool flag = false;
#pragma unroll
            for (int q = 0; q < TK; ++q) flag |= (tv[q] - tv[q + 1]) < THETA;
            const size_t gt = (size_t)(tok0 + lane) * TK;
            float2* ip = (float2*)(oidx + gt);
            float2* wp = (float2*)(ow + gt);
            ip[0] = make_float2((float)te[0], (float)te[1]);
            ip[1] = make_float2((float)te[2], (float)te[3]);
            ip[2] = make_float2((float)te[4], (float)te[5]);
            wp[0] = make_float2(ex[0] * rs, ex[1] * rs);
            wp[1] = make_float2(ex[2] * rs, ex[3] * rs);
            wp[2] = make_float2(ex[4] * rs, ex[5] * rs);
            if (!flag) {
#pragma unroll
                for (int q = 0; q < TK; ++q) atomicAdd(&cnt_s[te[q]], 1u);
            } else {
                const unsigned slot = atomicAdd(&nflag_s, 1u);
                flags_s[slot] = (unsigned)(wv * 64 + lane);  // <= 256 pushes
            }
        }
        const float sc = __expf(ml - mx) * rzt;
#pragma unroll
        for (int j = 0; j < 16; ++j)
            pi[j] = fmaf(acc[tt][j >> 2][j & 3], sc, pi[j]);
    }

    // Pi reduce across the 16 col-lanes sharing this lane's expert set
#pragma unroll
    for (int sh = 1; sh <= 8; sh <<= 1)
#pragma unroll
        for (int j = 0; j < 16; ++j) pi[j] += __shfl_xor(pi[j], sh);
    if (col == 0) {
#pragma unroll
        for (int j = 0; j < 16; ++j)
            Pi_s[wv][((j >> 2) << 4) + (g << 2) + (j & 3)] = pi[j];
    }
    __syncthreads();

    // ---- rescue: fp32 rescore flagged tokens, bit-identical to round-0 math.
    {
        const int nf = (int)nflag_s;            // uniform after barrier
        for (int i = wv; i < nf; i += 4) {
            const int tl = (int)flags_s[i];
            const float4* xr = (const float4*)(X + (size_t)(blockIdx.x * TPB + tl) * HID);
            const float4* wr = (const float4*)(W + (size_t)lane * HID);
            float a = 0.0f;
#pragma unroll 8
            for (int kq = 0; kq < 32; ++kq) {   // k strictly ascending 0..127
                const float4 xv = xr[kq];
                const float4 wv4 = wr[kq];
                a = fmaf(xv.x, wv4.x, a);
                a = fmaf(xv.y, wv4.y, a);
                a = fmaf(xv.z, wv4.z, a);
                a = fmaf(xv.w, wv4.w, a);
            }
            float tv[TK]; int ti[TK];
#pragma unroll
            for (int q = 0; q < TK; ++q) { tv[q] = -FLT_MAX; ti[q] = 0; }
            for (int e = 0; e < NE; ++e) {      // ascending e: stable tie order
                float m = __shfl(a, e);
                int  mi = e;
#pragma unroll
                for (int q = 0; q < TK; ++q) {
                    const bool  cx = m > tv[q];
                    const float nt = cx ? m     : tv[q];
                    const float nm = cx ? tv[q] : m;
                    const int   ni = cx ? mi    : ti[q];
                    const int   nj = cx ? ti[q] : mi;
                    tv[q] = nt; m = nm; ti[q] = ni; mi = nj;
                }
            }
            const float mx = tv[0];
            float ex[TK]; float s = 0.0f;
#pragma unroll
            for (int q = 0; q < TK; ++q) { ex[q] = __expf(tv[q] - mx); s += ex[q]; }
            const float rs = 1.0f / (s + 1e-20f);
            if (lane == 0) {
                const size_t gt = (size_t)(blockIdx.x * TPB + tl) * TK;
                float2* ip = (float2*)(oidx + gt);
                float2* wp = (float2*)(ow + gt);
                ip[0] = make_float2((float)ti[0], (float)ti[1]);
                ip[1] = make_float2((float)ti[2], (float)ti[3]);
                ip[2] = make_float2((float)ti[4], (float)ti[5]);
                wp[0] = make_float2(ex[0] * rs, ex[1] * rs);
                wp[1] = make_float2(ex[2] * rs, ex[3] * rs);
                wp[2] = make_float2(ex[4] * rs, ex[5] * rs);
#pragma unroll
                for (int q = 0; q < TK; ++q) atomicAdd(&cnt_s[ti[q]], 1u);
            }
        }
    }
    __syncthreads();

    if (tid < NE) {
        atomicAdd(&Pi_g[tid], Pi_s[0][tid] + Pi_s[1][tid] + Pi_s[2][tid] + Pi_s[3][tid]);
        atomicAdd(&cnt_g[tid], cnt_s[tid]);
    }
}

__global__ void aux_kernel(const float* __restrict__ Pi_g,
                           const unsigned int* __restrict__ cnt_g,
                           float* __restrict__ out_aux)
{
    const int e = threadIdx.x;   // 64 threads
    const float Pi = Pi_g[e] * (1.0f / (float)NTOK);
    const float ce = (float)cnt_g[e] * (1.0f / (float)(NTOK * TK));
    float v = Pi * ce * (float)NE;
#pragma unroll
    for (int off = 32; off > 0; off >>= 1) v += __shfl_down(v, off);
    if (e == 0) out_aux[0] = v * 1.0e-3f;
}

extern "C" void kernel_launch(void* const* d_in, const int* in_sizes, int n_in,
                              void* d_out, int out_size, void* d_ws, size_t ws_size,
                              hipStream_t stream) {
    const float* X = (const float*)d_in[0];
    const float* W = (const float*)d_in[1];

    float* out  = (float*)d_out;
    float* oidx = out;                          // N*6 indices (as float)
    float* ow   = out + (size_t)NTOK * TK;      // N*6 weights
    float* aux  = out + (size_t)NTOK * TK * 2;  // 1 scalar

    float*        Pi_g  = (float*)d_ws;
    unsigned int* cnt_g = (unsigned int*)((char*)d_ws + 256);

    hipMemsetAsync(d_ws, 0, 512, stream);
    gate_kernel<<<GRID, BLK, 0, stream>>>(X, W, oidx, ow, Pi_g, cnt_g);
    aux_kernel<<<1, 64, 0, stream>>>(Pi_g, cnt_g, aux);
}

// Round 7
// 249.728 us; speedup vs baseline: 3.1576x; 1.0617x over previous
//
#include <hip/hip_runtime.h>
#include <cfloat>

#define NTOK (64 * 4096)   // 262144 tokens
#define HID  128
#define NE   64
#define TK   6
#define TS   7             // sort depth: top-7 needed for the safety gap test
#define BLK  256
#define TPB  256           // tokens per block
#define GRID (NTOK / TPB)  // 1024 blocks
// Packed sort keys: key = (int(logit*2^17) << 6) | (63 - e).
//  - signed-int order == logit order (trunc monotone; |logit| << 256, no ovfl)
//  - unique keys -> jax tie order (lower e wins) automatic
//  - quant err <= 7.6e-6; MFMA err ~5e-5; flag iff key-gap < 1664 (~2e-4)
#define KSCALE 131072.0f
#define KINV   (1.0f / 131072.0f)
#define KTHR   1664

typedef __attribute__((ext_vector_type(8))) short short8;  // 8 bf16 (4 VGPRs)
typedef __attribute__((ext_vector_type(4))) float f32x4;   // MFMA C/D

union UB { uint4 u; short8 s; };
__device__ __forceinline__ short8 u2s(const uint4 u) { UB x; x.u = u; return x.s; }
__device__ __forceinline__ int imax(int a, int b) { return a > b ? a : b; }
__device__ __forceinline__ int imin(int a, int b) { return a < b ? a : b; }

// 2-term round-to-nearest split: a ~= a1 + a2, |a - a1 - a2| <= 2^-18 |a|.
__device__ __forceinline__ void split2(float a, float b, unsigned& d1, unsigned& d2) {
    unsigned p1;
    asm("v_cvt_pk_bf16_f32 %0, %1, %2" : "=v"(p1) : "v"(a), "v"(b));
    const float a1 = __uint_as_float(p1 << 16);
    const float b1 = __uint_as_float(p1 & 0xFFFF0000u);
    const float ra = a - a1;
    const float rb = b - b1;
    unsigned p2;
    asm("v_cvt_pk_bf16_f32 %0, %1, %2" : "=v"(p2) : "v"(ra), "v"(rb));
    d1 = p1; d2 = p2;
}

__device__ __forceinline__ void split8(const float4 v0, const float4 v1,
                                       uint4& o1, uint4& o2) {
    split2(v0.x, v0.y, o1.x, o2.x);
    split2(v0.z, v0.w, o1.y, o2.y);
    split2(v1.x, v1.y, o1.z, o2.z);
    split2(v1.z, v1.w, o1.w, o2.w);
}

// R5/R6-validated architecture: MFMA GEMM + gap flag + in-block fp32 rescue.
// R7 change (single subsystem): epilogue sort on packed int keys
// (v_max_i32/v_min_i32 compare-exchange, depth-1 chains, no index side-band).
__global__ __launch_bounds__(BLK)
void gate_kernel(const float* __restrict__ X,
                 const float* __restrict__ W,
                 float* __restrict__ oidx,
                 float* __restrict__ ow,
                 float* __restrict__ Pi_g,
                 unsigned int* __restrict__ cnt_g)
{
    __shared__ uint4        Wlds[2 * 1024];   // 32 KB: RNE-split W frags
    __shared__ float        Pi_s[4][NE];
    __shared__ unsigned int cnt_s[NE];
    __shared__ unsigned int flags_s[TPB];     // flagged token-local ids
    __shared__ unsigned int nflag_s;

    const int tid  = threadIdx.x;
    const int lane = tid & 63;
    const int wv   = __builtin_amdgcn_readfirstlane(tid >> 6);  // 0..3
    const int col  = lane & 15;
    const int g    = lane >> 4;

    if (tid < NE) cnt_s[tid] = 0u;
    if (tid == 0) nflag_s = 0u;

    // ---- one-time: RNE-split W (64x128 f32) into 2 bf16 frag arrays
    {
        const float4* W4 = (const float4*)W;
#pragma unroll
        for (int i = 0; i < 4; ++i) {
            const int slot = tid + i * BLK;          // [0,1024) = fid*64 + ln
            const int fid  = slot >> 6;              // et*4 + kt
            const int ln   = slot & 63;
            const int e    = ((fid >> 2) << 4) + (ln & 15);
            const int kq   = ((fid & 3) << 3) + ((ln >> 4) << 1);
            const float4 v0 = W4[e * 32 + kq];
            const float4 v1 = W4[e * 32 + kq + 1];
            uint4 o1, o2;
            split8(v0, v1, o1, o2);
            Wlds[slot]        = o1;
            Wlds[1024 + slot] = o2;
        }
    }
    __syncthreads();

    const int tok0 = blockIdx.x * TPB + wv * 64;

    f32x4 acc[4][4];   // [tt][et]
#pragma unroll
    for (int tt = 0; tt < 4; ++tt)
#pragma unroll
        for (int et = 0; et < 4; ++et) acc[tt][et] = (f32x4)0.0f;

    // ---- GEMM: 4 kt x {X-splits, 4 et x 4 products (w1x1,w1x2,w2x1,w2x2)}
#pragma unroll
    for (int kt = 0; kt < 4; ++kt) {
        uint4 xs[2][4];   // [split][tt]
#pragma unroll
        for (int tt = 0; tt < 4; ++tt) {
            const float4* xp = (const float4*)(X + (size_t)(tok0 + tt * 16 + col) * HID)
                               + (kt * 8 + g * 2);
            split8(xp[0], xp[1], xs[0][tt], xs[1][tt]);
        }
#pragma unroll
        for (int et = 0; et < 4; ++et) {
            const int fb = ((et << 2) + kt) * 64 + lane;
            const short8 w1 = u2s(Wlds[fb]);
            const short8 w2 = u2s(Wlds[1024 + fb]);
#define MM4(WF, XI) { \
            acc[0][et] = __builtin_amdgcn_mfma_f32_16x16x32_bf16(WF, u2s(xs[XI][0]), acc[0][et], 0, 0, 0); \
            acc[1][et] = __builtin_amdgcn_mfma_f32_16x16x32_bf16(WF, u2s(xs[XI][1]), acc[1][et], 0, 0, 0); \
            acc[2][et] = __builtin_amdgcn_mfma_f32_16x16x32_bf16(WF, u2s(xs[XI][2]), acc[2][et], 0, 0, 0); \
            acc[3][et] = __builtin_amdgcn_mfma_f32_16x16x32_bf16(WF, u2s(xs[XI][3]), acc[3][et], 0, 0, 0); }
            MM4(w1, 0) MM4(w1, 1) MM4(w2, 0) MM4(w2, 1)
#undef MM4
        }
    }

    // ---- epilogue: packed-key sort, registers + shuffles.
    // acc[tt][et][r] = logit(token = tok0+tt*16+col, expert = et*16+g*4+r)
    float pi[16];
#pragma unroll
    for (int j = 0; j < 16; ++j) pi[j] = 0.0f;

#pragma unroll
    for (int tt = 0; tt < 4; ++tt) {
        int tv[TS];
#pragma unroll
        for (int q = 0; q < TS; ++q) tv[q] = (int)0x80000000;
        // in-lane top-7-of-16 on packed keys (unique keys -> stability free)
#pragma unroll
        for (int j = 0; j < 16; ++j) {
            const float f = acc[tt][j >> 2][j & 3];
            const int  ik = (int)(f * KSCALE);
            const int   e = ((j >> 2) << 4) + (g << 2) + (j & 3);
            int m = (int)(((unsigned)ik << 6) | (unsigned)(63 - e));
#pragma unroll
            for (int q = 0; q < TS; ++q) {
                const int t = tv[q];
                tv[q] = imax(t, m);
                m     = imin(t, m);
            }
        }
        const float ml = (float)(tv[0] >> 6) * KINV;   // quantized lane max
        float Zl = 0.0f;
#pragma unroll
        for (int j = 0; j < 16; ++j) {
            const float e = __expf(acc[tt][j >> 2][j & 3] - ml);
            acc[tt][j >> 2][j & 3] = e;                // keep exp for Pi pass
            Zl += e;
        }
        // merge the 4 lane-groups' sorted 7-lists: levels xor 16, 32
        float m_self = ml, Z = Zl;
#pragma unroll
        for (int lv = 16; lv <= 32; lv <<= 1) {
            int rv[TS];
#pragma unroll
            for (int q = 0; q < TS; ++q) rv[q] = __shfl_xor(tv[q], lv);
            const float m_p = (float)(rv[0] >> 6) * KINV;
            const float Z_p = __shfl_xor(Z, lv);
#pragma unroll
            for (int q2 = 0; q2 < TS; ++q2) {
                int m = rv[q2];
#pragma unroll
                for (int q = 0; q < TS; ++q) {
                    const int t = tv[q];
                    tv[q] = imax(t, m);
                    m     = imin(t, m);
                }
            }
            const float m_n = (float)(tv[0] >> 6) * KINV;
            Z = Z * __expf(m_self - m_n) + Z_p * __expf(m_p - m_n);
            m_self = m_n;
        }
        const float mx  = (float)(tv[0] >> 6) * KINV;  // quantized global max
        const float rzt = 1.0f / Z;
        float ex[TK]; float s = 0.0f;
#pragma unroll
        for (int q = 0; q < TK; ++q) {
            ex[q] = __expf((float)(tv[q] >> 6) * KINV - mx);
            s += ex[q];
        }
        const float rs = 1.0f / (s + 1e-20f);
        if (g == tt) {                          // writer lane: token = tok0 + lane
            bool flag = false;
#pragma unroll
            for (int q = 0; q < TK; ++q) flag |= (tv[q] - tv[q + 1]) < KTHR;
            int te[TK];
#pragma unroll
            for (int q = 0; q < TK; ++q) te[q] = 63 - (tv[q] & 63);
            const size_t gt = (size_t)(tok0 + lane) * TK;
            float2* ip = (float2*)(oidx + gt);
            float2* wp = (float2*)(ow + gt);
            ip[0] = make_float2((float)te[0], (float)te[1]);
            ip[1] = make_float2((float)te[2], (float)te[3]);
            ip[2] = make_float2((float)te[4], (float)te[5]);
            wp[0] = make_float2(ex[0] * rs, ex[1] * rs);
            wp[1] = make_float2(ex[2] * rs, ex[3] * rs);
            wp[2] = make_float2(ex[4] * rs, ex[5] * rs);
            if (!flag) {
#pragma unroll
                for (int q = 0; q < TK; ++q) atomicAdd(&cnt_s[te[q]], 1u);
            } else {
                const unsigned slot = atomicAdd(&nflag_s, 1u);
                flags_s[slot] = (unsigned)(wv * 64 + lane);  // <= 256 pushes
            }
        }
        const float sc = __expf(ml - mx) * rzt;
#pragma unroll
        for (int j = 0; j < 16; ++j)
            pi[j] = fmaf(acc[tt][j >> 2][j & 3], sc, pi[j]);
    }

    // Pi reduce across the 16 col-lanes sharing this lane's expert set
#pragma unroll
    for (int sh = 1; sh <= 8; sh <<= 1)
#pragma unroll
        for (int j = 0; j < 16; ++j) pi[j] += __shfl_xor(pi[j], sh);
    if (col == 0) {
#pragma unroll
        for (int j = 0; j < 16; ++j)
            Pi_s[wv][((j >> 2) << 4) + (g << 2) + (j & 3)] = pi[j];
    }
    __syncthreads();

    // ---- rescue: fp32 rescore flagged tokens, bit-identical to round-0 math.
    // (exact fp32 path: packed keys NOT used here by design)
    {
        const int nf = (int)nflag_s;            // uniform after barrier
        for (int i = wv; i < nf; i += 4) {
            const int tl = (int)flags_s[i];
            const float4* xr = (const float4*)(X + (size_t)(blockIdx.x * TPB + tl) * HID);
            const float4* wr = (const float4*)(W + (size_t)lane * HID);
            float a = 0.0f;
#pragma unroll 8
            for (int kq = 0; kq < 32; ++kq) {   // k strictly ascending 0..127
                const float4 xv = xr[kq];
                const float4 wv4 = wr[kq];
                a = fmaf(xv.x, wv4.x, a);
                a = fmaf(xv.y, wv4.y, a);
                a = fmaf(xv.z, wv4.z, a);
                a = fmaf(xv.w, wv4.w, a);
            }
            float tv[TK]; int ti[TK];
#pragma unroll
            for (int q = 0; q < TK; ++q) { tv[q] = -FLT_MAX; ti[q] = 0; }
            for (int e = 0; e < NE; ++e) {      // ascending e: stable tie order
                float m = __shfl(a, e);
                int  mi = e;
#pragma unroll
                for (int q = 0; q < TK; ++q) {
                    const bool  cx = m > tv[q];
                    const float nt = cx ? m     : tv[q];
                    const float nm = cx ? tv[q] : m;
                    const int   ni = cx ? mi    : ti[q];
                    const int   nj = cx ? ti[q] : mi;
                    tv[q] = nt; m = nm; ti[q] = ni; mi = nj;
                }
            }
            const float mx = tv[0];
            float ex[TK]; float s = 0.0f;
#pragma unroll
            for (int q = 0; q < TK; ++q) { ex[q] = __expf(tv[q] - mx); s += ex[q]; }
            const float rs = 1.0f / (s + 1e-20f);
            if (lane == 0) {
                const size_t gt = (size_t)(blockIdx.x * TPB + tl) * TK;
                float2* ip = (float2*)(oidx + gt);
                float2* wp = (float2*)(ow + gt);
                ip[0] = make_float2((float)ti[0], (float)ti[1]);
                ip[1] = make_float2((float)ti[2], (float)ti[3]);
                ip[2] = make_float2((float)ti[4], (float)ti[5]);
                wp[0] = make_float2(ex[0] * rs, ex[1] * rs);
                wp[1] = make_float2(ex[2] * rs, ex[3] * rs);
                wp[2] = make_float2(ex[4] * rs, ex[5] * rs);
#pragma unroll
                for (int q = 0; q < TK; ++q) atomicAdd(&cnt_s[ti[q]], 1u);
            }
        }
    }
    __syncthreads();

    if (tid < NE) {
        atomicAdd(&Pi_g[tid], Pi_s[0][tid] + Pi_s[1][tid] + Pi_s[2][tid] + Pi_s[3][tid]);
        atomicAdd(&cnt_g[tid], cnt_s[tid]);
    }
}

__global__ void aux_kernel(const float* __restrict__ Pi_g,
                           const unsigned int* __restrict__ cnt_g,
                           float* __restrict__ out_aux)
{
    const int e = threadIdx.x;   // 64 threads
    const float Pi = Pi_g[e] * (1.0f / (float)NTOK);
    const float ce = (float)cnt_g[e] * (1.0f / (float)(NTOK * TK));
    float v = Pi * ce * (float)NE;
#pragma unroll
    for (int off = 32; off > 0; off >>= 1) v += __shfl_down(v, off);
    if (e == 0) out_aux[0] = v * 1.0e-3f;
}

extern "C" void kernel_launch(void* const* d_in, const int* in_sizes, int n_in,
                              void* d_out, int out_size, void* d_ws, size_t ws_size,
                              hipStream_t stream) {
    const float* X = (const float*)d_in[0];
    const float* W = (const float*)d_in[1];

    float* out  = (float*)d_out;
    float* oidx = out;                          // N*6 indices (as float)
    float* ow   = out + (size_t)NTOK * TK;      // N*6 weights
    float* aux  = out + (size_t)NTOK * TK * 2;  // 1 scalar

    float*        Pi_g  = (float*)d_ws;
    unsigned int* cnt_g = (unsigned int*)((char*)d_ws + 256);

    hipMemsetAsync(d_ws, 0, 512, stream);
    gate_kernel<<<GRID, BLK, 0, stream>>>(X, W, oidx, ow, Pi_g, cnt_g);
    aux_kernel<<<1, 64, 0, stream>>>(Pi_g, cnt_g, aux);
}

// Round 8
// 245.141 us; speedup vs baseline: 3.2167x; 1.0187x over previous
//
#include <hip/hip_runtime.h>
#include <cfloat>

#define NTOK (64 * 4096)   // 262144 tokens
#define HID  128
#define NE   64
#define TK   6
#define TS   7             // sort depth: top-7 needed for the safety gap test
#define BLK  256
#define TPB  256           // tokens per block
#define GRID (NTOK / TPB)  // 1024 blocks
#define LST  67            // logit row stride: 67%32=3 coprime -> b32 conflict-free
// Packed sort keys (R7-proven): key = (int(logit*2^17) << 6) | (63 - e).
#define KSCALE 131072.0f
#define KINV   (1.0f / 131072.0f)
#define KTHR   1664        // ~2e-4 in key units; MFMA+quant err ~6e-5 << KTHR/2

typedef __attribute__((ext_vector_type(8))) short short8;  // 8 bf16 (4 VGPRs)
typedef __attribute__((ext_vector_type(4))) float f32x4;   // MFMA C/D

union UB { uint4 u; short8 s; };
__device__ __forceinline__ short8 u2s(const uint4 u) { UB x; x.u = u; return x.s; }
__device__ __forceinline__ int imax(int a, int b) { return a > b ? a : b; }
__device__ __forceinline__ int imin(int a, int b) { return a < b ? a : b; }

// 2-term round-to-nearest split: a ~= a1 + a2, |a - a1 - a2| <= 2^-18 |a|.
__device__ __forceinline__ void split2(float a, float b, unsigned& d1, unsigned& d2) {
    unsigned p1;
    asm("v_cvt_pk_bf16_f32 %0, %1, %2" : "=v"(p1) : "v"(a), "v"(b));
    const float a1 = __uint_as_float(p1 << 16);
    const float b1 = __uint_as_float(p1 & 0xFFFF0000u);
    const float ra = a - a1;
    const float rb = b - b1;
    unsigned p2;
    asm("v_cvt_pk_bf16_f32 %0, %1, %2" : "=v"(p2) : "v"(ra), "v"(rb));
    d1 = p1; d2 = p2;
}

__device__ __forceinline__ void split8(const float4 v0, const float4 v1,
                                       uint4& o1, uint4& o2) {
    split2(v0.x, v0.y, o1.x, o2.x);
    split2(v0.z, v0.w, o1.y, o2.y);
    split2(v1.x, v1.y, o1.z, o2.z);
    split2(v1.z, v1.w, o1.w, o2.w);
}

// R8: MFMA GEMM (R5-R7 proven) + R4-proven logit scatter into the R0-proven
// L[t][e] stride-67 LDS layout + thread-per-token packed-key epilogue (no
// cross-lane merges) + R0-proven Pi pass + R5-R7-proven flag/rescue.
// Residency evidence (R0/R2 vs R5-R7): ~1.5 blocks/CU resident regardless of
// LDS 35K vs 68K -> the 72 KB LDS here is empirically free.
__global__ __launch_bounds__(BLK)
void gate_kernel(const float* __restrict__ X,
                 const float* __restrict__ W,
                 float* __restrict__ oidx,
                 float* __restrict__ ow,
                 float* __restrict__ Pi_g,
                 unsigned int* __restrict__ cnt_g)
{
    // Phase GEMM: smem[0..8192) overlaid as uint4 Wlds[2*1024] (32 KB W frags)
    // Phase EPI : smem[0..256*67) = logits L[t][e] at t*LST+e (after barrier)
    __shared__ __align__(16) float smem[TPB * LST];   // 68.6 KB
    __shared__ float        mz[2 * TPB];
    __shared__ float        Pi_s[NE];
    __shared__ unsigned int cnt_s[NE];
    __shared__ unsigned int flags_s[TPB];
    __shared__ unsigned int nflag_s;

    uint4* Wlds = (uint4*)smem;

    const int tid  = threadIdx.x;
    const int lane = tid & 63;
    const int wv   = __builtin_amdgcn_readfirstlane(tid >> 6);  // 0..3
    const int col  = lane & 15;
    const int g    = lane >> 4;
    const int eb   = wv * 16;                  // Pi pass: wave's 16 experts

    if (tid < NE) cnt_s[tid] = 0u;
    if (tid == 0) nflag_s = 0u;

    // ---- one-time: RNE-split W (64x128 f32) into 2 bf16 frag arrays
    {
        const float4* W4 = (const float4*)W;
#pragma unroll
        for (int i = 0; i < 4; ++i) {
            const int slot = tid + i * BLK;          // [0,1024) = fid*64 + ln
            const int fid  = slot >> 6;              // et*4 + kt
            const int ln   = slot & 63;
            const int e    = ((fid >> 2) << 4) + (ln & 15);
            const int kq   = ((fid & 3) << 3) + ((ln >> 4) << 1);
            const float4 v0 = W4[e * 32 + kq];
            const float4 v1 = W4[e * 32 + kq + 1];
            uint4 o1, o2;
            split8(v0, v1, o1, o2);
            Wlds[slot]        = o1;
            Wlds[1024 + slot] = o2;
        }
    }
    __syncthreads();

    const int tok0 = blockIdx.x * TPB + wv * 64;

    f32x4 acc[4][4];   // [tt][et]
#pragma unroll
    for (int tt = 0; tt < 4; ++tt)
#pragma unroll
        for (int et = 0; et < 4; ++et) acc[tt][et] = (f32x4)0.0f;

    // ---- GEMM: 4 kt x {X-splits, 4 et x 4 products (w1x1,w1x2,w2x1,w2x2)}
#pragma unroll
    for (int kt = 0; kt < 4; ++kt) {
        uint4 xs[2][4];   // [split][tt]
#pragma unroll
        for (int tt = 0; tt < 4; ++tt) {
            const float4* xp = (const float4*)(X + (size_t)(tok0 + tt * 16 + col) * HID)
                               + (kt * 8 + g * 2);
            split8(xp[0], xp[1], xs[0][tt], xs[1][tt]);
        }
#pragma unroll
        for (int et = 0; et < 4; ++et) {
            const int fb = ((et << 2) + kt) * 64 + lane;
            const short8 w1 = u2s(Wlds[fb]);
            const short8 w2 = u2s(Wlds[1024 + fb]);
#define MM4(WF, XI) { \
            acc[0][et] = __builtin_amdgcn_mfma_f32_16x16x32_bf16(WF, u2s(xs[XI][0]), acc[0][et], 0, 0, 0); \
            acc[1][et] = __builtin_amdgcn_mfma_f32_16x16x32_bf16(WF, u2s(xs[XI][1]), acc[1][et], 0, 0, 0); \
            acc[2][et] = __builtin_amdgcn_mfma_f32_16x16x32_bf16(WF, u2s(xs[XI][2]), acc[2][et], 0, 0, 0); \
            acc[3][et] = __builtin_amdgcn_mfma_f32_16x16x32_bf16(WF, u2s(xs[XI][3]), acc[3][et], 0, 0, 0); }
            MM4(w1, 0) MM4(w1, 1) MM4(w2, 0) MM4(w2, 1)
#undef MM4
        }
    }

    __syncthreads();   // all waves done reading Wlds -> overlay region with logits

    // ---- scatter logits (R4-proven glue): L[t][e] = smem[t*67+e]
    // acc[tt][et][r] = logit(token = tok0+tt*16+col, expert = et*16+g*4+r)
#pragma unroll
    for (int tt = 0; tt < 4; ++tt) {
        const int trow = (wv * 64 + tt * 16 + col) * LST;
#pragma unroll
        for (int et = 0; et < 4; ++et) {
            float* p = &smem[trow + et * 16 + g * 4];
            p[0] = acc[tt][et][0];
            p[1] = acc[tt][et][1];
            p[2] = acc[tt][et][2];
            p[3] = acc[tt][et][3];
        }
    }
    __syncthreads();

    // ---- epilogue: thread = token; flat packed-key top-7 over 64 (no merges)
    {
        const int t = tid;
        const float* Lrow = &smem[t * LST];
        int tv[TS];
#pragma unroll
        for (int q = 0; q < TS; ++q) tv[q] = (int)0x80000000;

#pragma unroll 8
        for (int e = 0; e < NE; ++e) {         // ascending e; unique keys ->
            const float f = Lrow[e];           // jax tie order automatic
            int m = (int)(((unsigned)((int)(f * KSCALE)) << 6) | (unsigned)(63 - e));
#pragma unroll
            for (int q = 0; q < TS; ++q) {
                const int c = tv[q];
                tv[q] = imax(c, m);
                m     = imin(c, m);
            }
        }

        const float mx = (float)(tv[0] >> 6) * KINV;   // quantized global max
        float ex[TK]; float s = 0.0f;
#pragma unroll
        for (int q = 0; q < TK; ++q) {
            ex[q] = __expf((float)(tv[q] >> 6) * KINV - mx);
            s += ex[q];
        }
        const float rs = 1.0f / (s + 1e-20f);
        int te[TK];
#pragma unroll
        for (int q = 0; q < TK; ++q) te[q] = 63 - (tv[q] & 63);

        const size_t gt = (size_t)(blockIdx.x * TPB + t) * TK;
        float2* ip = (float2*)(oidx + gt);
        float2* wp = (float2*)(ow + gt);
        ip[0] = make_float2((float)te[0], (float)te[1]);
        ip[1] = make_float2((float)te[2], (float)te[3]);
        ip[2] = make_float2((float)te[4], (float)te[5]);
        wp[0] = make_float2(ex[0] * rs, ex[1] * rs);
        wp[1] = make_float2(ex[2] * rs, ex[3] * rs);
        wp[2] = make_float2(ex[4] * rs, ex[5] * rs);

        bool flag = false;
#pragma unroll
        for (int q = 0; q < TK; ++q) flag |= (tv[q] - tv[q + 1]) < KTHR;
        if (!flag) {
#pragma unroll
            for (int q = 0; q < TK; ++q) atomicAdd(&cnt_s[te[q]], 1u);
        } else {
            const unsigned slot = atomicAdd(&nflag_s, 1u);
            flags_s[slot] = (unsigned)t;
        }

        float Z = 0.0f;
#pragma unroll 8
        for (int e = 0; e < NE; ++e) Z += __expf(Lrow[e] - mx);
        mz[2*t]     = mx;
        mz[2*t + 1] = 1.0f / Z;
    }
    __syncthreads();

    // ---- Pi (R0-proven): re-read logits; lane's 4 tokens x wave's 16 experts
    {
        float pi[16];
#pragma unroll
        for (int j = 0; j < 16; ++j) pi[j] = 0.0f;
#pragma unroll
        for (int gg = 0; gg < 4; ++gg) {
            const int t = lane + 64 * gg;
            const float mxt = mz[2*t];
            const float rzt = mz[2*t + 1];
            const float* p = &smem[t * LST + eb];
#pragma unroll
            for (int j = 0; j < 16; ++j)
                pi[j] += __expf(p[j] - mxt) * rzt;
        }
#pragma unroll
        for (int s = 1; s <= 32; s <<= 1) {
#pragma unroll
            for (int j = 0; j < 16; ++j) pi[j] += __shfl_xor(pi[j], s);
        }
        if (lane < 16) Pi_s[eb + lane] = pi[lane];   // waves own disjoint experts
    }
    __syncthreads();

    // ---- rescue: fp32 rescore flagged tokens, bit-identical to round-0 math.
    {
        const int nf = (int)nflag_s;            // uniform after barrier
        for (int i = wv; i < nf; i += 4) {
            const int tl = (int)flags_s[i];
            const float4* xr = (const float4*)(X + (size_t)(blockIdx.x * TPB + tl) * HID);
            const float4* wr = (const float4*)(W + (size_t)lane * HID);
            float a = 0.0f;
#pragma unroll 8
            for (int kq = 0; kq < 32; ++kq) {   // k strictly ascending 0..127
                const float4 xv = xr[kq];
                const float4 wv4 = wr[kq];
                a = fmaf(xv.x, wv4.x, a);
                a = fmaf(xv.y, wv4.y, a);
                a = fmaf(xv.z, wv4.z, a);
                a = fmaf(xv.w, wv4.w, a);
            }
            float tv[TK]; int ti[TK];
#pragma unroll
            for (int q = 0; q < TK; ++q) { tv[q] = -FLT_MAX; ti[q] = 0; }
            for (int e = 0; e < NE; ++e) {      // ascending e: stable tie order
                float m = __shfl(a, e);
                int  mi = e;
#pragma unroll
                for (int q = 0; q < TK; ++q) {
                    const bool  cx = m > tv[q];
                    const float nt = cx ? m     : tv[q];
                    const float nm = cx ? tv[q] : m;
                    const int   ni = cx ? mi    : ti[q];
                    const int   nj = cx ? ti[q] : mi;
                    tv[q] = nt; m = nm; ti[q] = ni; mi = nj;
                }
            }
            const float mx = tv[0];
            float ex[TK]; float s = 0.0f;
#pragma unroll
            for (int q = 0; q < TK; ++q) { ex[q] = __expf(tv[q] - mx); s += ex[q]; }
            const float rs = 1.0f / (s + 1e-20f);
            if (lane == 0) {
                const size_t gt = (size_t)(blockIdx.x * TPB + tl) * TK;
                float2* ip = (float2*)(oidx + gt);
                float2* wp = (float2*)(ow + gt);
                ip[0] = make_float2((float)ti[0], (float)ti[1]);
                ip[1] = make_float2((float)ti[2], (float)ti[3]);
                ip[2] = make_float2((float)ti[4], (float)ti[5]);
                wp[0] = make_float2(ex[0] * rs, ex[1] * rs);
                wp[1] = make_float2(ex[2] * rs, ex[3] * rs);
                wp[2] = make_float2(ex[4] * rs, ex[5] * rs);
#pragma unroll
                for (int q = 0; q < TK; ++q) atomicAdd(&cnt_s[ti[q]], 1u);
            }
        }
    }
    __syncthreads();

    if (tid < NE) {
        atomicAdd(&Pi_g[tid], Pi_s[tid]);
        atomicAdd(&cnt_g[tid], cnt_s[tid]);
    }
}

__global__ void aux_kernel(const float* __restrict__ Pi_g,
                           const unsigned int* __restrict__ cnt_g,
                           float* __restrict__ out_aux)
{
    const int e = threadIdx.x;   // 64 threads
    const float Pi = Pi_g[e] * (1.0f / (float)NTOK);
    const float ce = (float)cnt_g[e] * (1.0f / (float)(NTOK * TK));
    float v = Pi * ce * (float)NE;
#pragma unroll
    for (int off = 32; off > 0; off >>= 1) v += __shfl_down(v, off);
    if (e == 0) out_aux[0] = v * 1.0e-3f;
}

extern "C" void kernel_launch(void* const* d_in, const int* in_sizes, int n_in,
                              void* d_out, int out_size, void* d_ws, size_t ws_size,
                              hipStream_t stream) {
    const float* X = (const float*)d_in[0];
    const float* W = (const float*)d_in[1];

    float* out  = (float*)d_out;
    float* oidx = out;                          // N*6 indices (as float)
    float* ow   = out + (size_t)NTOK * TK;      // N*6 weights
    float* aux  = out + (size_t)NTOK * TK * 2;  // 1 scalar

    float*        Pi_g  = (float*)d_ws;
    unsigned int* cnt_g = (unsigned int*)((char*)d_ws + 256);

    hipMemsetAsync(d_ws, 0, 512, stream);
    gate_kernel<<<GRID, BLK, 0, stream>>>(X, W, oidx, ow, Pi_g, cnt_g);
    aux_kernel<<<1, 64, 0, stream>>>(Pi_g, cnt_g, aux);
}